// Round 6
// baseline (791.689 us; speedup 1.0000x reference)
//
#include <hip/hip_runtime.h>
#include <math.h>

#define IMN 1024
#define IMGSZ (IMN * IMN)
#define NIMG 6
#define EPSV 0.001f
#define LDK 44   // LDS row stride (u16): 88 B = 22 words -> <=2-way banks (free) for
                 // both b128 frag reads (stride pattern 22L mod 32 distinct over 16 lanes)
                 // and 16B staging writes. 16B-aligned rows.
#define NB1 4096

typedef unsigned short u16;
typedef __attribute__((ext_vector_type(8))) short short8;     // 8 bf16 = 4 VGPRs
typedef __attribute__((ext_vector_type(16))) float floatx16;  // 32x32 C/D

__device__ __forceinline__ u16 rne_bf16(float v) {
  unsigned u = __float_as_uint(v);
  u = u + 0x7FFFu + ((u >> 16) & 1u);
  return (u16)(u >> 16);
}

// ---------------------------------------------------------------------------
__global__ __launch_bounds__(256) void build_taps_k(float* __restrict__ taps) {
  const int kss[3] = {91, 481, 1501};
  const float sig[3] = {15.f, 80.f, 250.f};
  int s = blockIdx.x;
  int ks = kss[s];
  float sigma = sig[s];
  float* t = taps + s * 1536;
  float ctr = (float)(ks - 1) * 0.5f;
  __shared__ float red[256];
  float loc = 0.f;
  for (int i = threadIdx.x; i < ks; i += 256) {
    float x = ((float)i - ctr) / sigma;
    float v = expf(-0.5f * x * x);
    t[i] = v;
    loc += v;
  }
  red[threadIdx.x] = loc;
  __syncthreads();
  for (int o = 128; o > 0; o >>= 1) {
    if (threadIdx.x < o) red[threadIdx.x] += red[threadIdx.x + o];
    __syncthreads();
  }
  float inv = 1.f / red[0];
  for (int i = threadIdx.x; i < ks; i += 256) t[i] *= inv;
}

// ---------------------------------------------------------------------------
// W[r,j] = sum of taps with reflect(r+t-p)==j; stored as bf16 hi (RNE) + lo (RNE resid).
__global__ __launch_bounds__(256) void build_w_k(const float* __restrict__ taps, int ks,
                                                 u16* __restrict__ WHr, u16* __restrict__ WLr) {
  int r = blockIdx.x;
  int p = ks >> 1;
  __shared__ float row[IMN];
  for (int i = threadIdx.x; i < IMN; i += 256) row[i] = 0.f;
  __syncthreads();
  for (int t = threadIdx.x; t < ks; t += 256) {
    int q = r + t - p;
    int j = q < 0 ? -q : (q > IMN - 1 ? 2 * (IMN - 1) - q : q);
    atomicAdd(&row[j], taps[t]);
  }
  __syncthreads();
  for (int i = threadIdx.x; i < IMN; i += 256) {
    float v = row[i];
    u16 h = rne_bf16(v);
    float hf = __uint_as_float((unsigned)h << 16);
    WHr[r * IMN + i] = h;
    WLr[r * IMN + i] = rne_bf16(v - hf);
  }
}

// ---------------------------------------------------------------------------
// clip(img) -> single bf16 (RNE) plane. (A-operand is hi-only: lo img term is
// fully 2D-blurred downstream -> smooth ~1e-3 in log, negligible for loss.)
__global__ __launch_bounds__(256) void split_img_k(const float* __restrict__ inp,
                                                   u16* __restrict__ H) {
  int i4 = (blockIdx.x * 256 + threadIdx.x) * 4;
  float4 v = *(const float4*)&inp[i4];
  float x[4] = {v.x, v.y, v.z, v.w};
  u16 h[4];
#pragma unroll
  for (int e = 0; e < 4; e++) h[e] = rne_bf16(fminf(fmaxf(x[e], EPSV), 1.f));
  *(uint2*)&H[i4] = make_uint2((unsigned)h[0] | ((unsigned)h[1] << 16),
                               (unsigned)h[2] | ((unsigned)h[3] << 16));
}

// ---------------------------------------------------------------------------
// bf16x2 MFMA GEMM (A-hi x (B-hi + B-lo)), 128x128 tile, 32x32x16, wave 64x64.
// Flat-grid XCD swizzle: blocks sharing an A tile share blockIdx%8 (same XCD
// under round-robin) -> A fetched ~once per XCD L2.
// EPI=0: A = imgH[i], B = WH/WL[s]; out OH[z] = bf16 U, stored transposed.
// EPI=1: A = UtH[z],  B = WH/WL[s]; out OF[outByZ? z : i] = log(max(blur,eps)).
template <int EPI>
__global__ __launch_bounds__(256, 4) void gemm_pass(
    const u16* __restrict__ AH, const u16* __restrict__ WH, const u16* __restrict__ WL,
    u16* __restrict__ OH, float* __restrict__ OF, int sBase, int outByZ, int rmw) {
  __shared__ u16 smem[3 * 128 * LDK];  // 33792 B
  u16* Ah = smem;
  u16* Bh = smem + 128 * LDK;
  u16* Bl = smem + 2 * 128 * LDK;
  int flat = blockIdx.x;
  int r = flat & 7;
  int t = flat >> 3;
  int bnIdx = t & 7;
  int z = t >> 3;
  int s = sBase + z / 6;
  int i = z - (z / 6) * 6;
  int key = (EPI == 0) ? i : z;          // blocks sharing an A tile
  int bmIdx = (r - key) & 7;
  int bm = bmIdx * 128, bn = bnIdx * 128;
  const u16* Ag = AH + (size_t)(EPI == 0 ? i : z) * IMGSZ;
  const u16* BgH = WH + (size_t)s * IMGSZ;
  const u16* BgL = WL + (size_t)s * IMGSZ;
  int tid = threadIdx.x;
  int lane = tid & 63, w = tid >> 6;
  int wm = (w >> 1) * 64, wn = (w & 1) * 64;
  int lrow = lane & 31, lh = lane >> 5;
  int tr = tid >> 2, tc = (tid & 3) * 8;  // staging: 4 threads/row, 16 B each
  floatx16 acc[2][2] = {};

  for (int k0 = 0; k0 < IMN; k0 += 32) {
    uint4 a0 = *(const uint4*)&Ag[(size_t)(bm + tr) * IMN + k0 + tc];
    uint4 a1 = *(const uint4*)&Ag[(size_t)(bm + tr + 64) * IMN + k0 + tc];
    uint4 b0h = *(const uint4*)&BgH[(size_t)(bn + tr) * IMN + k0 + tc];
    uint4 b1h = *(const uint4*)&BgH[(size_t)(bn + tr + 64) * IMN + k0 + tc];
    uint4 b0l = *(const uint4*)&BgL[(size_t)(bn + tr) * IMN + k0 + tc];
    uint4 b1l = *(const uint4*)&BgL[(size_t)(bn + tr + 64) * IMN + k0 + tc];
    *(uint4*)&Ah[tr * LDK + tc] = a0;
    *(uint4*)&Ah[(tr + 64) * LDK + tc] = a1;
    *(uint4*)&Bh[tr * LDK + tc] = b0h;
    *(uint4*)&Bh[(tr + 64) * LDK + tc] = b1h;
    *(uint4*)&Bl[tr * LDK + tc] = b0l;
    *(uint4*)&Bl[(tr + 64) * LDK + tc] = b1l;
    __syncthreads();
#pragma unroll
    for (int kk = 0; kk < 32; kk += 16) {
      short8 ah[2], bh[2], bl[2];
#pragma unroll
      for (int mt = 0; mt < 2; mt++)
        ah[mt] = *(const short8*)&Ah[(wm + mt * 32 + lrow) * LDK + kk + lh * 8];
#pragma unroll
      for (int nt = 0; nt < 2; nt++) {
        int off = (wn + nt * 32 + lrow) * LDK + kk + lh * 8;
        bh[nt] = *(const short8*)&Bh[off];
        bl[nt] = *(const short8*)&Bl[off];
      }
#pragma unroll
      for (int mt = 0; mt < 2; mt++)
#pragma unroll
        for (int nt = 0; nt < 2; nt++) {
          acc[mt][nt] = __builtin_amdgcn_mfma_f32_32x32x16_bf16(ah[mt], bh[nt], acc[mt][nt], 0, 0, 0);
          acc[mt][nt] = __builtin_amdgcn_mfma_f32_32x32x16_bf16(ah[mt], bl[nt], acc[mt][nt], 0, 0, 0);
        }
    }
    __syncthreads();
  }

  // Epilogue: per-wave 32x32 LDS transpose (stride 33, free), coalesced rows.
  // C/D: col(n)=lane&31, row(m)=(reg&3)+8*(reg>>2)+4*(lane>>5) [verified R3/R5].
  // lf is wave-private (no barriers needed; compiler orders LDS via lgkmcnt).
  float* lf = (float*)smem + w * 1056;  // 4 x 4224 B = 16896 <= 33792
#pragma unroll
  for (int mt = 0; mt < 2; mt++)
#pragma unroll
    for (int nt = 0; nt < 2; nt++) {
#pragma unroll
      for (int rq = 0; rq < 4; rq++)
#pragma unroll
        for (int e = 0; e < 4; e++)
          lf[lrow * 33 + rq * 8 + lh * 4 + e] = acc[mt][nt][rq * 4 + e];
#pragma unroll
      for (int p = 0; p < 4; p++) {
        int rl = p * 8 + (lane >> 3);
        int cl = (lane & 7) * 4;
        float v0 = lf[rl * 33 + cl + 0];
        float v1 = lf[rl * 33 + cl + 1];
        float v2 = lf[rl * 33 + cl + 2];
        float v3 = lf[rl * 33 + cl + 3];
        int gn = bn + wn + nt * 32 + rl;  // output row
        int gm = bm + wm + mt * 32 + cl;  // output col
        if (EPI == 0) {
          size_t go = (size_t)z * IMGSZ + (size_t)gn * IMN + gm;
          *(uint2*)&OH[go] = make_uint2(
              (unsigned)rne_bf16(v0) | ((unsigned)rne_bf16(v1) << 16),
              (unsigned)rne_bf16(v2) | ((unsigned)rne_bf16(v3) << 16));
        } else {
          size_t go = (size_t)(outByZ ? z : i) * IMGSZ + (size_t)gn * IMN + gm;
          float4 rr = make_float4(logf(fmaxf(v0, EPSV)), logf(fmaxf(v1, EPSV)),
                                  logf(fmaxf(v2, EPSV)), logf(fmaxf(v3, EPSV)));
          if (rmw) {
            float4 pa = *(const float4*)&OF[go];
            rr.x += pa.x; rr.y += pa.y; rr.z += pa.z; rr.w += pa.w;
          }
          *(float4*)&OF[go] = rr;
        }
      }
    }
}

// ---------------------------------------------------------------------------
__global__ __launch_bounds__(256) void loss_stage1_k(const float* __restrict__ inp,
                                                     const float* __restrict__ lb, int three,
                                                     float* __restrict__ refl,
                                                     float* __restrict__ illum,
                                                     float* __restrict__ pd,
                                                     float* __restrict__ ps) {
  const int stride = NB1 * 256;
  const int S = NIMG * IMGSZ;
  float sd = 0.f, ss = 0.f;
  for (int i = blockIdx.x * 256 + threadIdx.x; i < S; i += stride) {
    int c = i & (IMN - 1);
    int rr = (i >> 10) & (IMN - 1);
    float a0 = lb[i];
    if (three) a0 += lb[i + S] + lb[i + 2 * S];
    float I0 = a0 * (1.f / 3.f);
    float R0 = logf(fmaxf(inp[i], EPSV)) - I0;
    refl[i] = R0;
    illum[i] = I0;
    if (c < IMN - 1) {
      float a1 = lb[i + 1];
      if (three) a1 += lb[i + 1 + S] + lb[i + 1 + 2 * S];
      float I1 = a1 * (1.f / 3.f);
      float R1 = logf(fmaxf(inp[i + 1], EPSV)) - I1;
      sd += fabsf(R0 - R1);
      ss += fabsf(I0 - I1);
    }
    if (rr < IMN - 1) {
      float a2 = lb[i + IMN];
      if (three) a2 += lb[i + IMN + S] + lb[i + IMN + 2 * S];
      float I2 = a2 * (1.f / 3.f);
      float R2 = logf(fmaxf(inp[i + IMN], EPSV)) - I2;
      sd += fabsf(R0 - R2);
      ss += fabsf(I0 - I2);
    }
  }
  for (int o = 32; o > 0; o >>= 1) {
    sd += __shfl_down(sd, o);
    ss += __shfl_down(ss, o);
  }
  __shared__ float rsd[4], rss[4];
  int lane = threadIdx.x & 63, w = threadIdx.x >> 6;
  if (lane == 0) { rsd[w] = sd; rss[w] = ss; }
  __syncthreads();
  if (threadIdx.x == 0) {
    pd[blockIdx.x] = rsd[0] + rsd[1] + rsd[2] + rsd[3];
    ps[blockIdx.x] = rss[0] + rss[1] + rss[2] + rss[3];
  }
}

__global__ __launch_bounds__(256) void loss_stage2_k(const float* __restrict__ pd,
                                                     const float* __restrict__ ps,
                                                     float* __restrict__ out) {
  float sd = 0.f, ss = 0.f;
  for (int i = threadIdx.x; i < NB1; i += 256) {
    sd += pd[i];
    ss += ps[i];
  }
  for (int o = 32; o > 0; o >>= 1) {
    sd += __shfl_down(sd, o);
    ss += __shfl_down(ss, o);
  }
  __shared__ float rsd[4], rss[4];
  int lane = threadIdx.x & 63, w = threadIdx.x >> 6;
  if (lane == 0) { rsd[w] = sd; rss[w] = ss; }
  __syncthreads();
  if (threadIdx.x == 0) {
    float tsd = rsd[0] + rsd[1] + rsd[2] + rsd[3];
    float tss = rss[0] + rss[1] + rss[2] + rss[3];
    const float sc = 1.f / 6285312.f;  // 2*3*1024*1023
    out[0] = tss * sc;
    out[1] = tsd * sc;
    out[2] = tss * sc;
  }
}

// ---------------------------------------------------------------------------
extern "C" void kernel_launch(void* const* d_in, const int* in_sizes, int n_in,
                              void* d_out, int out_size, void* d_ws, size_t ws_size,
                              hipStream_t stream) {
  const float* inp = (const float*)d_in[0];
  float* out = (float*)d_out;
  float* refl = out + 3;
  float* illum = refl + (size_t)NIMG * IMGSZ;
  const int kss[3] = {91, 481, 1501};

  char* p = (char*)d_ws;
  float* taps = (float*)p;                  p += 32768;
  u16* WH = (u16*)p;                        p += (size_t)3 * IMGSZ * 2;
  u16* WL = (u16*)p;                        p += (size_t)3 * IMGSZ * 2;
  u16* imgH = (u16*)p;                      p += (size_t)NIMG * IMGSZ * 2;
  size_t fixed = (size_t)(p - (char*)d_ws);
  // Tier1 (z=18, one dispatch/pass): Ut 18 bf16 planes (36 MB) + LB 18 fp32 (72 MB) = ~132 MB.
  size_t needT1 = fixed + (size_t)18 * IMGSZ * 2 + (size_t)18 * IMGSZ * 4;
  bool t1 = ws_size >= needT1;
  int nz = t1 ? 18 : 6;
  u16* UtH = (u16*)p;                       p += (size_t)nz * IMGSZ * 2;
  float* LB = (float*)p;  // t1: 18 log-blur planes; t2: 6-plane fp32 accumulator
  float* pd = taps;       // overlay dead taps region
  float* ps = taps + NB1;

  build_taps_k<<<3, 256, 0, stream>>>(taps);
  for (int s = 0; s < 3; s++)
    build_w_k<<<IMN, 256, 0, stream>>>(taps + s * 1536, kss[s],
                                       WH + (size_t)s * IMGSZ, WL + (size_t)s * IMGSZ);
  split_img_k<<<NIMG * IMGSZ / 1024, 256, 0, stream>>>(inp, imgH);

  if (t1) {
    gemm_pass<0><<<18 * 64, 256, 0, stream>>>(imgH, WH, WL, UtH, nullptr, 0, 1, 0);
    gemm_pass<1><<<18 * 64, 256, 0, stream>>>(UtH, WH, WL, nullptr, LB, 0, 1, 0);
  } else {
    for (int s = 0; s < 3; s++) {
      gemm_pass<0><<<6 * 64, 256, 0, stream>>>(imgH, WH, WL, UtH, nullptr, s, 0, 0);
      gemm_pass<1><<<6 * 64, 256, 0, stream>>>(UtH, WH, WL, nullptr, LB, s, 0, s > 0);
    }
  }
  loss_stage1_k<<<NB1, 256, 0, stream>>>(inp, LB, t1 ? 1 : 0, refl, illum, pd, ps);
  loss_stage2_k<<<1, 256, 0, stream>>>(pd, ps, out);
}

// Round 7
// 312.820 us; speedup vs baseline: 2.5308x; 2.5308x over previous
//
#include <hip/hip_runtime.h>
#include <math.h>

#define IMN 1024
#define IMGSZ (IMN * IMN)
#define NIMG 6
#define EPSV 0.001f
#define LDK 40   // LDS row stride (u16): 80 B — 16B-ALIGNED rows (critical: LDK=44's
                 // 88 B rows put odd-row b128 DS ops at 8-mod-16 addresses -> round-6
                 // 2.3x regression). Known cost: 4-way frag-read conflict (~1.58x LDS).
#define NB1 4096

typedef unsigned short u16;
typedef __attribute__((ext_vector_type(8))) short short8;     // 8 bf16 = 4 VGPRs
typedef __attribute__((ext_vector_type(16))) float floatx16;  // 32x32 C/D

__device__ __forceinline__ u16 rne_bf16(float v) {
  unsigned u = __float_as_uint(v);
  u = u + 0x7FFFu + ((u >> 16) & 1u);
  return (u16)(u >> 16);
}

// ---------------------------------------------------------------------------
__global__ __launch_bounds__(256) void build_taps_k(float* __restrict__ taps) {
  const int kss[3] = {91, 481, 1501};
  const float sig[3] = {15.f, 80.f, 250.f};
  int s = blockIdx.x;
  int ks = kss[s];
  float sigma = sig[s];
  float* t = taps + s * 1536;
  float ctr = (float)(ks - 1) * 0.5f;
  __shared__ float red[256];
  float loc = 0.f;
  for (int i = threadIdx.x; i < ks; i += 256) {
    float x = ((float)i - ctr) / sigma;
    float v = expf(-0.5f * x * x);
    t[i] = v;
    loc += v;
  }
  red[threadIdx.x] = loc;
  __syncthreads();
  for (int o = 128; o > 0; o >>= 1) {
    if (threadIdx.x < o) red[threadIdx.x] += red[threadIdx.x + o];
    __syncthreads();
  }
  float inv = 1.f / red[0];
  for (int i = threadIdx.x; i < ks; i += 256) t[i] *= inv;
}

// ---------------------------------------------------------------------------
// W[r,j] = sum of taps with reflect(r+t-p)==j; stored as bf16 hi (RNE) + lo (RNE resid).
__global__ __launch_bounds__(256) void build_w_k(const float* __restrict__ taps, int ks,
                                                 u16* __restrict__ WHr, u16* __restrict__ WLr) {
  int r = blockIdx.x;
  int p = ks >> 1;
  __shared__ float row[IMN];
  for (int i = threadIdx.x; i < IMN; i += 256) row[i] = 0.f;
  __syncthreads();
  for (int t = threadIdx.x; t < ks; t += 256) {
    int q = r + t - p;
    int j = q < 0 ? -q : (q > IMN - 1 ? 2 * (IMN - 1) - q : q);
    atomicAdd(&row[j], taps[t]);
  }
  __syncthreads();
  for (int i = threadIdx.x; i < IMN; i += 256) {
    float v = row[i];
    u16 h = rne_bf16(v);
    float hf = __uint_as_float((unsigned)h << 16);
    WHr[r * IMN + i] = h;
    WLr[r * IMN + i] = rne_bf16(v - hf);
  }
}

// ---------------------------------------------------------------------------
// clip(img) -> single bf16 (RNE) plane (A is hi-only; validated in round 6).
__global__ __launch_bounds__(256) void split_img_k(const float* __restrict__ inp,
                                                   u16* __restrict__ H) {
  int i4 = (blockIdx.x * 256 + threadIdx.x) * 4;
  float4 v = *(const float4*)&inp[i4];
  float x[4] = {v.x, v.y, v.z, v.w};
  u16 h[4];
#pragma unroll
  for (int e = 0; e < 4; e++) h[e] = rne_bf16(fminf(fmaxf(x[e], EPSV), 1.f));
  *(uint2*)&H[i4] = make_uint2((unsigned)h[0] | ((unsigned)h[1] << 16),
                               (unsigned)h[2] | ((unsigned)h[3] << 16));
}

// ---------------------------------------------------------------------------
// bf16x2 MFMA GEMM (A-hi x (B-hi + B-lo)), 128x128 tile, 32x32x16, wave 64x64.
// ROUND-5 PROVEN STRUCTURE: 3-D grid (x=bn, y=bm, z), no flat swizzle.
// EPI=0: A = imgH[i], B = WH/WL[s]; out OH[z] = bf16 U, stored transposed.
// EPI=1: A = UtH[z],  B = WH/WL[s]; out OF[outByZ? z : i] = log(max(blur,eps)).
template <int EPI>
__global__ __launch_bounds__(256, 4) void gemm_pass(
    const u16* __restrict__ AH, const u16* __restrict__ WH, const u16* __restrict__ WL,
    u16* __restrict__ OH, float* __restrict__ OF, int sBase, int outByZ, int rmw) {
  __shared__ u16 smem[3 * 128 * LDK];  // 30720 B -> up to 5 blocks/CU
  u16* Ah = smem;
  u16* Bh = smem + 128 * LDK;
  u16* Bl = smem + 2 * 128 * LDK;
  int z = blockIdx.z;
  int s = sBase + z / 6;
  int i = z - (z / 6) * 6;
  const u16* Ag = AH + (size_t)(EPI == 0 ? i : z) * IMGSZ;
  const u16* BgH = WH + (size_t)s * IMGSZ;
  const u16* BgL = WL + (size_t)s * IMGSZ;
  int bm = blockIdx.y * 128, bn = blockIdx.x * 128;
  int tid = threadIdx.x;
  int lane = tid & 63, w = tid >> 6;
  int wm = (w >> 1) * 64, wn = (w & 1) * 64;
  int lrow = lane & 31, lh = lane >> 5;
  int tr = tid >> 2, tc = (tid & 3) * 8;  // staging: 4 threads/row, 16 B each
  floatx16 acc[2][2] = {};

  for (int k0 = 0; k0 < IMN; k0 += 32) {
    uint4 a0 = *(const uint4*)&Ag[(size_t)(bm + tr) * IMN + k0 + tc];
    uint4 a1 = *(const uint4*)&Ag[(size_t)(bm + tr + 64) * IMN + k0 + tc];
    uint4 b0h = *(const uint4*)&BgH[(size_t)(bn + tr) * IMN + k0 + tc];
    uint4 b1h = *(const uint4*)&BgH[(size_t)(bn + tr + 64) * IMN + k0 + tc];
    uint4 b0l = *(const uint4*)&BgL[(size_t)(bn + tr) * IMN + k0 + tc];
    uint4 b1l = *(const uint4*)&BgL[(size_t)(bn + tr + 64) * IMN + k0 + tc];
    *(uint4*)&Ah[tr * LDK + tc] = a0;
    *(uint4*)&Ah[(tr + 64) * LDK + tc] = a1;
    *(uint4*)&Bh[tr * LDK + tc] = b0h;
    *(uint4*)&Bh[(tr + 64) * LDK + tc] = b1h;
    *(uint4*)&Bl[tr * LDK + tc] = b0l;
    *(uint4*)&Bl[(tr + 64) * LDK + tc] = b1l;
    __syncthreads();
#pragma unroll
    for (int kk = 0; kk < 32; kk += 16) {
      short8 ah[2], bh[2], bl[2];
#pragma unroll
      for (int mt = 0; mt < 2; mt++)
        ah[mt] = *(const short8*)&Ah[(wm + mt * 32 + lrow) * LDK + kk + lh * 8];
#pragma unroll
      for (int nt = 0; nt < 2; nt++) {
        int off = (wn + nt * 32 + lrow) * LDK + kk + lh * 8;
        bh[nt] = *(const short8*)&Bh[off];
        bl[nt] = *(const short8*)&Bl[off];
      }
#pragma unroll
      for (int mt = 0; mt < 2; mt++)
#pragma unroll
        for (int nt = 0; nt < 2; nt++) {
          acc[mt][nt] = __builtin_amdgcn_mfma_f32_32x32x16_bf16(ah[mt], bh[nt], acc[mt][nt], 0, 0, 0);
          acc[mt][nt] = __builtin_amdgcn_mfma_f32_32x32x16_bf16(ah[mt], bl[nt], acc[mt][nt], 0, 0, 0);
        }
    }
    __syncthreads();
  }

  // Epilogue (round-5 proven): per-wave 32x32 LDS transpose (stride 33),
  // coalesced row stores. C/D: col(n)=lane&31, row(m)=(reg&3)+8*(reg>>2)+4*(lane>>5).
  float* lf = (float*)smem + w * 1056;  // 4 x 4224 B = 16896 <= 30720
#pragma unroll
  for (int mt = 0; mt < 2; mt++)
#pragma unroll
    for (int nt = 0; nt < 2; nt++) {
#pragma unroll
      for (int rq = 0; rq < 4; rq++)
#pragma unroll
        for (int e = 0; e < 4; e++)
          lf[lrow * 33 + rq * 8 + lh * 4 + e] = acc[mt][nt][rq * 4 + e];
      __syncthreads();
#pragma unroll
      for (int p = 0; p < 4; p++) {
        int rl = p * 8 + (lane >> 3);
        int cl = (lane & 7) * 4;
        float v0 = lf[rl * 33 + cl + 0];
        float v1 = lf[rl * 33 + cl + 1];
        float v2 = lf[rl * 33 + cl + 2];
        float v3 = lf[rl * 33 + cl + 3];
        int gn = bn + wn + nt * 32 + rl;  // output row
        int gm = bm + wm + mt * 32 + cl;  // output col
        if (EPI == 0) {
          size_t go = (size_t)z * IMGSZ + (size_t)gn * IMN + gm;  // keep plane offset!
          *(uint2*)&OH[go] = make_uint2(
              (unsigned)rne_bf16(v0) | ((unsigned)rne_bf16(v1) << 16),
              (unsigned)rne_bf16(v2) | ((unsigned)rne_bf16(v3) << 16));
        } else {
          size_t go = (size_t)(outByZ ? z : i) * IMGSZ + (size_t)gn * IMN + gm;
          float4 rr = make_float4(logf(fmaxf(v0, EPSV)), logf(fmaxf(v1, EPSV)),
                                  logf(fmaxf(v2, EPSV)), logf(fmaxf(v3, EPSV)));
          if (rmw) {
            float4 pa = *(const float4*)&OF[go];
            rr.x += pa.x; rr.y += pa.y; rr.z += pa.z; rr.w += pa.w;
          }
          *(float4*)&OF[go] = rr;
        }
      }
      __syncthreads();
    }
}

// ---------------------------------------------------------------------------
__global__ __launch_bounds__(256) void loss_stage1_k(const float* __restrict__ inp,
                                                     const float* __restrict__ lb, int three,
                                                     float* __restrict__ refl,
                                                     float* __restrict__ illum,
                                                     float* __restrict__ pd,
                                                     float* __restrict__ ps) {
  const int stride = NB1 * 256;
  const int S = NIMG * IMGSZ;
  float sd = 0.f, ss = 0.f;
  for (int i = blockIdx.x * 256 + threadIdx.x; i < S; i += stride) {
    int c = i & (IMN - 1);
    int rr = (i >> 10) & (IMN - 1);
    float a0 = lb[i];
    if (three) a0 += lb[i + S] + lb[i + 2 * S];
    float I0 = a0 * (1.f / 3.f);
    float R0 = logf(fmaxf(inp[i], EPSV)) - I0;
    refl[i] = R0;
    illum[i] = I0;
    if (c < IMN - 1) {
      float a1 = lb[i + 1];
      if (three) a1 += lb[i + 1 + S] + lb[i + 1 + 2 * S];
      float I1 = a1 * (1.f / 3.f);
      float R1 = logf(fmaxf(inp[i + 1], EPSV)) - I1;
      sd += fabsf(R0 - R1);
      ss += fabsf(I0 - I1);
    }
    if (rr < IMN - 1) {
      float a2 = lb[i + IMN];
      if (three) a2 += lb[i + IMN + S] + lb[i + IMN + 2 * S];
      float I2 = a2 * (1.f / 3.f);
      float R2 = logf(fmaxf(inp[i + IMN], EPSV)) - I2;
      sd += fabsf(R0 - R2);
      ss += fabsf(I0 - I2);
    }
  }
  for (int o = 32; o > 0; o >>= 1) {
    sd += __shfl_down(sd, o);
    ss += __shfl_down(ss, o);
  }
  __shared__ float rsd[4], rss[4];
  int lane = threadIdx.x & 63, w = threadIdx.x >> 6;
  if (lane == 0) { rsd[w] = sd; rss[w] = ss; }
  __syncthreads();
  if (threadIdx.x == 0) {
    pd[blockIdx.x] = rsd[0] + rsd[1] + rsd[2] + rsd[3];
    ps[blockIdx.x] = rss[0] + rss[1] + rss[2] + rss[3];
  }
}

__global__ __launch_bounds__(256) void loss_stage2_k(const float* __restrict__ pd,
                                                     const float* __restrict__ ps,
                                                     float* __restrict__ out) {
  float sd = 0.f, ss = 0.f;
  for (int i = threadIdx.x; i < NB1; i += 256) {
    sd += pd[i];
    ss += ps[i];
  }
  for (int o = 32; o > 0; o >>= 1) {
    sd += __shfl_down(sd, o);
    ss += __shfl_down(ss, o);
  }
  __shared__ float rsd[4], rss[4];
  int lane = threadIdx.x & 63, w = threadIdx.x >> 6;
  if (lane == 0) { rsd[w] = sd; rss[w] = ss; }
  __syncthreads();
  if (threadIdx.x == 0) {
    float tsd = rsd[0] + rsd[1] + rsd[2] + rsd[3];
    float tss = rss[0] + rss[1] + rss[2] + rss[3];
    const float sc = 1.f / 6285312.f;  // 2*3*1024*1023
    out[0] = tss * sc;
    out[1] = tsd * sc;
    out[2] = tss * sc;
  }
}

// ---------------------------------------------------------------------------
extern "C" void kernel_launch(void* const* d_in, const int* in_sizes, int n_in,
                              void* d_out, int out_size, void* d_ws, size_t ws_size,
                              hipStream_t stream) {
  const float* inp = (const float*)d_in[0];
  float* out = (float*)d_out;
  float* refl = out + 3;
  float* illum = refl + (size_t)NIMG * IMGSZ;
  const int kss[3] = {91, 481, 1501};

  char* p = (char*)d_ws;
  float* taps = (float*)p;                  p += 32768;
  u16* WH = (u16*)p;                        p += (size_t)3 * IMGSZ * 2;
  u16* WL = (u16*)p;                        p += (size_t)3 * IMGSZ * 2;
  u16* imgH = (u16*)p;                      p += (size_t)NIMG * IMGSZ * 2;
  size_t fixed = (size_t)(p - (char*)d_ws);
  // Tier1 (z=18, one dispatch/pass): Ut 18 bf16 planes (36 MB) + LB 18 fp32 (72 MB).
  size_t needT1 = fixed + (size_t)18 * IMGSZ * 2 + (size_t)18 * IMGSZ * 4;
  bool t1 = ws_size >= needT1;
  int nz = t1 ? 18 : 6;
  u16* UtH = (u16*)p;                       p += (size_t)nz * IMGSZ * 2;
  float* LB = (float*)p;  // t1: 18 log-blur planes; t2: 6-plane fp32 accumulator
  float* pd = taps;       // overlay dead taps region
  float* ps = taps + NB1;

  build_taps_k<<<3, 256, 0, stream>>>(taps);
  for (int s = 0; s < 3; s++)
    build_w_k<<<IMN, 256, 0, stream>>>(taps + s * 1536, kss[s],
                                       WH + (size_t)s * IMGSZ, WL + (size_t)s * IMGSZ);
  split_img_k<<<NIMG * IMGSZ / 1024, 256, 0, stream>>>(inp, imgH);

  if (t1) {
    dim3 g(8, 8, 18);
    gemm_pass<0><<<g, 256, 0, stream>>>(imgH, WH, WL, UtH, nullptr, 0, 1, 0);
    gemm_pass<1><<<g, 256, 0, stream>>>(UtH, WH, WL, nullptr, LB, 0, 1, 0);
  } else {
    dim3 g(8, 8, 6);
    for (int s = 0; s < 3; s++) {
      gemm_pass<0><<<g, 256, 0, stream>>>(imgH, WH, WL, UtH, nullptr, s, 0, 0);
      gemm_pass<1><<<g, 256, 0, stream>>>(UtH, WH, WL, nullptr, LB, s, 0, s > 0);
    }
  }
  loss_stage1_k<<<NB1, 256, 0, stream>>>(inp, LB, t1 ? 1 : 0, refl, illum, pd, ps);
  loss_stage2_k<<<1, 256, 0, stream>>>(pd, ps, out);
}